// Round 6
// baseline (241.687 us; speedup 1.0000x reference)
//
#include <hip/hip_runtime.h>
#include <hip/hip_fp16.h>

#define WIDTH   640
#define HEIGHT  384
#define PLANE   (WIDTH*HEIGHT)
#define STRIP_H 24
#define NSTRIP  16                /* 384/24 */
#define GROUPS  6                 /* 4 output rows per group */
#define NBLK    (96*NSTRIP*2)     /* 3072 = 3 exact rounds of 4 blocks/CU */
#define SEGW    320               /* output cols per block (column half) */
#define LCOLS   330               /* owned cols incl 5-col halo each side */
#define CS_W    336               /* padded stride */
#define RING_D  12
#define SSIM_C1 1.0e-4f
#define SSIM_C2 9.0e-4f
#define INV_N   (1.0f/23592960.0f)

__device__ __forceinline__ __half2 packh2(float a, float b) {
    // single v_cvt_pkrtz_f16_f32; rtz quantization is consistent add/sub so no drift
    __fp16 __attribute__((ext_vector_type(2))) v = __builtin_amdgcn_cvt_pkrtz(a, b);
    __half2 r;
    __builtin_memcpy(&r, &v, sizeof(r));
    return r;
}

// 4-row groups on a 320-col half-strip: LDS = ring 16.1 KB + cs 21.5 KB =
// 37.6 KB -> 4 blocks/CU (vs 3). Ring is thread-private (col ownership) so
// only cs needs the A->B barrier. Phase B keeps the proven conflict-free
// stride-5 rolling shape: wave w <-> output row w, 64 lanes x 5 px = 320.
__global__ __launch_bounds__(256, 4)
void ssim_main(const float* __restrict__ pred, const float* __restrict__ targ,
               float* __restrict__ ws)
{
    __shared__ __half2 ring[RING_D][CS_W];  // raw (p,t) fp16 pairs, 16.1 KB
    __shared__ float   cs[4][4][CS_W];      // [krow][comp][slot], 21.5 KB
    __shared__ float   red[4];

    const int tid   = threadIdx.x;
    const int plane = blockIdx.x % 96;      // neighbors differ by 96 -> same XCD
    const int rest  = blockIdx.x / 96;      // 0..31
    const int strip = rest >> 1;            // 0..15
    const int half  = rest & 1;
    const int y0    = strip * STRIP_H;
    const int x0    = half * SEGW;
    const float* __restrict__ P = pred + plane * PLANE;
    const float* __restrict__ T = targ + plane * PLANE;

    // col ownership: o=tid for all threads; 74 extra cols (256..329) spread
    // across waves ((tid&3)-interleaved) to balance Phase-A work ~1.1:1
    const int  q    = tid >> 2, m4 = tid & 3;
    const bool own1 = (m4 == 3) || (m4 == 2 && tid < 40);
    int  oo[2]; bool own[2], vx[2]; int gx[2];
    oo[0] = tid;                          own[0] = true;
    oo[1] = 256 + ((m4 == 3) ? q : 64 + q); own[1] = own1;
#pragma unroll
    for (int ci = 0; ci < 2; ++ci) {
        gx[ci] = x0 - 5 + oo[ci];
        vx[ci] = own[ci] && (gx[ci] >= 0) && (gx[ci] < WIDTH);
    }

    // ---- Bootstrap: rows [y0-6, y0+4] -> ring slots 0..10, column sums for
    //      the window of output row y0-1 (arithmetic on quantized fp16).
    //      Off-image cols write zeros -> halo cs slots are correct by default.
    float S[2][4];
#pragma unroll
    for (int ci = 0; ci < 2; ++ci) { S[ci][0]=S[ci][1]=S[ci][2]=S[ci][3]=0.f; }

#pragma unroll
    for (int ci = 0; ci < 2; ++ci) {
        if (own[ci]) {
#pragma unroll
            for (int j = 0; j < 11; ++j) {
                int yy = y0 - 6 + j;
                float p = 0.f, t = 0.f;
                if (vx[ci] && yy >= 0) { p = P[yy*WIDTH + gx[ci]]; t = T[yy*WIDTH + gx[ci]]; }
                __half2 h = packh2(p, t);
                ring[j][oo[ci]] = h;
                float2 v = __half22float2(h);
                S[ci][0] += v.x;  S[ci][1] += v.y;
                S[ci][2] += v.x*v.x + v.y*v.y;
                S[ci][3] += v.x*v.y;
            }
        }
    }

    // prefetch registers for the four rows entering the window each group
    float pfP[2][4], pfT[2][4];
    auto do_prefetch = [&](int gg) {
        const int yb = y0 + (gg << 2) + 5;
#pragma unroll
        for (int ci = 0; ci < 2; ++ci) {
            if (own[ci]) {
#pragma unroll
                for (int k = 0; k < 4; ++k) {
                    int yn = yb + k;
                    bool v = vx[ci] && (yn < HEIGHT);
                    pfP[ci][k] = v ? P[yn*WIDTH + gx[ci]] : 0.f;
                    pfT[ci][k] = v ? T[yn*WIDTH + gx[ci]] : 0.f;
                }
            }
        }
    };
    do_prefetch(0);

    float acc = 0.f;
    const float inv121 = 1.0f / 121.0f;
    int rs = 0;   // ring slot of the row subtracted at k=0 of this group

#pragma clang loop unroll(disable)
    for (int g = 0; g < GROUPS; ++g) {
        // consume prefetched rows into locals, then issue next group's loads
        // -> VMEM latency overlaps rest of A + barrier + B + barrier
        float cP[2][4], cT[2][4];
#pragma unroll
        for (int ci = 0; ci < 2; ++ci)
#pragma unroll
            for (int k = 0; k < 4; ++k) { cP[ci][k] = pfP[ci][k]; cT[ci][k] = pfT[ci][k]; }

        if (g + 1 < GROUPS) do_prefetch(g + 1);

        // ---- Phase A: advance 4 rows; per k: subtract ring[rs+k], write new
        //      row into slot (rs+k+11)%12 (freed by k-1's subtract)
#pragma unroll
        for (int ci = 0; ci < 2; ++ci) {
            if (own[ci]) {
                const int o = oo[ci];
#pragma unroll
                for (int k = 0; k < 4; ++k) {
                    int ss = rs + k;                 // 0..11, no wrap (rs<=8)
                    int sa = ss + 11; if (sa >= RING_D) sa -= RING_D;
                    __half2 hn = packh2(cP[ci][k], cT[ci][k]);
                    __half2 ho = ring[ss][o];
                    ring[sa][o] = hn;
                    float2 nq = __half22float2(hn);  // use quantized value
                    float2 o2 = __half22float2(ho);
                    S[ci][0] += nq.x - o2.x;
                    S[ci][1] += nq.y - o2.y;
                    S[ci][2] += nq.x*nq.x + nq.y*nq.y - o2.x*o2.x - o2.y*o2.y;
                    S[ci][3] += nq.x*nq.y - o2.x*o2.y;
                    cs[k][0][o] = S[ci][0];
                    cs[k][1][o] = S[ci][1];
                    cs[k][2][o] = S[ci][2];
                    cs[k][3][o] = S[ci][3];
                }
            }
        }
        __syncthreads();

        // ---- Phase B: wave w = output row w; 64 lanes x 5 px; full 15-slot
        //      window read once into regs (lane stride 5 -> conflict-free),
        //      then all rolling arithmetic register-resident
        {
            const int w    = tid >> 6;
            const int base = (tid & 63) * 5;
            float W[4][5];
#pragma unroll
            for (int comp = 0; comp < 4; ++comp) {
                float s[15];
#pragma unroll
                for (int j = 0; j < 15; ++j) s[j] = cs[w][comp][base + j];
                float b = s[0];
#pragma unroll
                for (int j = 1; j < 11; ++j) b += s[j];
                W[comp][0] = b;
#pragma unroll
                for (int i = 1; i < 5; ++i) { b += s[10+i] - s[i-1]; W[comp][i] = b; }
            }
#pragma unroll
            for (int i = 0; i < 5; ++i) {
                float mp  = W[0][i] * inv121, mt = W[1][i] * inv121;
                float mpp = mp*mp, mtt = mt*mt, mpt = mp*mt;
                float s2  = W[2][i] * inv121 - mpp - mtt;   // sigma_p + sigma_t
                float spt = W[3][i] * inv121 - mpt;         // sigma_pt
                float num = (2.f*mpt + SSIM_C1) * (2.f*spt + SSIM_C2);
                float den = (mpp + mtt + SSIM_C1) * (s2 + SSIM_C2);
                acc += num * __builtin_amdgcn_rcpf(den);
            }
        }
        __syncthreads();   // WAR: B reads done before next A overwrites cs

        rs += 4; if (rs >= RING_D) rs -= RING_D;
    }

    // ---- block reduction -> one plain store per block (no atomics)
#pragma unroll
    for (int off = 32; off >= 1; off >>= 1)
        acc += __shfl_down(acc, off);
    if ((tid & 63) == 0) red[tid >> 6] = acc;
    __syncthreads();
    if (tid == 0)
        ws[blockIdx.x] = red[0] + red[1] + red[2] + red[3];
}

__global__ void ssim_reduce(const float* __restrict__ ws, float* __restrict__ out)
{
    __shared__ float red[4];
    const int tid = threadIdx.x;
    float s = 0.f;
#pragma unroll
    for (int i = 0; i < 12; ++i) s += ws[tid + (i << 8)];
#pragma unroll
    for (int off = 32; off >= 1; off >>= 1)
        s += __shfl_down(s, off);
    if ((tid & 63) == 0) red[tid >> 6] = s;
    __syncthreads();
    if (tid == 0)
        out[0] = 1.0f - (red[0] + red[1] + red[2] + red[3]) * INV_N;
}

extern "C" void kernel_launch(void* const* d_in, const int* in_sizes, int n_in,
                              void* d_out, int out_size, void* d_ws, size_t ws_size,
                              hipStream_t stream) {
    const float* pred = (const float*)d_in[0];
    const float* targ = (const float*)d_in[1];
    float* out = (float*)d_out;
    float* ws  = (float*)d_ws;          // 3072 floats of partial sums
    ssim_main<<<NBLK, 256, 0, stream>>>(pred, targ, ws);
    ssim_reduce<<<1, 256, 0, stream>>>(ws, out);
}

// Round 7
// 222.339 us; speedup vs baseline: 1.0870x; 1.0870x over previous
//
#include <hip/hip_runtime.h>
#include <hip/hip_fp16.h>

#define WIDTH   640
#define HEIGHT  384
#define PLANE   (WIDTH*HEIGHT)
#define STRIP_H 48
#define NSTRIP  8                 /* 384/48 */
#define GROUPS  24                /* STRIP_H/2 */
#define NBLK    (96*NSTRIP)       /* 768 = 3 blocks/CU exactly */
#define CS_W    656               /* slots 0..649 used, slot = x+5 */
#define SSIM_C1 1.0e-4f
#define SSIM_C2 9.0e-4f
#define INV_N   (1.0f/23592960.0f)

__device__ __forceinline__ __half2 packh2(float a, float b) {
    // single v_cvt_pkrtz_f16_f32; rtz quantization is consistent add/sub so no drift
    __fp16 __attribute__((ext_vector_type(2))) v = __builtin_amdgcn_cvt_pkrtz(a, b);
    __half2 r;
    __builtin_memcpy(&r, &v, sizeof(r));
    return r;
}
__device__ __forceinline__ float2 f2add(float2 a, float2 b) {
    return make_float2(a.x + b.x, a.y + b.y);   // -> v_pk_add_f32
}
__device__ __forceinline__ float2 f2sub(float2 a, float2 b) {
    return make_float2(a.x - b.x, a.y - b.y);
}

// Round-3 structure + float2-paired column sums. The LDS PORT was the hidden
// co-bottleneck (zero conflicts but ~110 ds-instr/wave/group at ~5cyc each):
// pairing comps into b64 ops cuts Phase B 76->30 and Phase A writes 4->2.
// b64 bank math: read lane-stride 10 dwords / write stride 2 dwords -> every
// bank serves exactly 4 of 64 lanes = b64's natural minimum -> conflict-free.
__global__ __launch_bounds__(256, 3)
void ssim_main(const float* __restrict__ pred, const float* __restrict__ targ,
               float* __restrict__ ws)
{
    __shared__ __half2 ring[11][WIDTH];   // raw (p,t) fp16 pairs, 28.2 KB
    __shared__ float2  csA[2][CS_W];      // {Sp, St}        10.5 KB
    __shared__ float2  csB[2][CS_W];      // {Spp+Stt, Spt}  10.5 KB
    __shared__ float   red[4];

    const int tid   = threadIdx.x;
    const int plane = blockIdx.x % 96;      // vertical neighbors differ by 96 -> same XCD
    const int strip = blockIdx.x / 96;      // 0..7
    const int y0s   = strip * STRIP_H;
    const float* __restrict__ P = pred + plane * PLANE;
    const float* __restrict__ T = targ + plane * PLANE;

    // zero horizontal-halo cs slots once (Phase A never touches them; first
    // Phase-B read is after the first barrier, which orders this write)
    if (tid < 20) {
        int k = tid / 10, j = tid % 10;
        int s = (j < 5) ? j : (640 + j);    // {0..4, 645..649}
        csA[k][s] = make_float2(0.f, 0.f);
        csB[k][s] = make_float2(0.f, 0.f);
    }

    // ---- Bootstrap: stage rows [y0s-6, y0s+4] into ring, build column sums
    //      for output row y0s-1 (all arithmetic on the quantized fp16 values)
    float2 S01[3], S23[3];
#pragma unroll
    for (int c = 0; c < 3; ++c) {
        S01[c] = make_float2(0.f, 0.f);
        S23[c] = make_float2(0.f, 0.f);
    }

#pragma unroll
    for (int c = 0; c < 3; ++c) {
        int x = tid + (c << 8);
        if (x < WIDTH) {
            for (int j = 0; j < 11; ++j) {
                int yy = y0s - 6 + j;
                __half2 h = (yy >= 0) ? packh2(P[yy*WIDTH+x], T[yy*WIDTH+x])
                                      : packh2(0.f, 0.f);
                ring[j][x] = h;
                float2 v = __half22float2(h);
                S01[c] = f2add(S01[c], v);
                S23[c] = f2add(S23[c], make_float2(v.x*v.x + v.y*v.y, v.x*v.y));
            }
        }
    }

    // prefetch registers for the two rows entering the window each group
    float pfP[3][2], pfT[3][2];
    auto do_prefetch = [&](int gg) {
        const int y0 = y0s + (gg << 1);
#pragma unroll
        for (int k = 0; k < 2; ++k) {
            int yn = y0 + k + 5;
            if (yn < HEIGHT) {              // uniform -> scalar branch
#pragma unroll
                for (int c = 0; c < 3; ++c) {
                    int x = tid + (c << 8);
                    if (x < WIDTH) {
                        pfP[c][k] = P[yn*WIDTH + x];
                        pfT[c][k] = T[yn*WIDTH + x];
                    }
                }
            } else {
#pragma unroll
                for (int c = 0; c < 3; ++c) { pfP[c][k] = 0.f; pfT[c][k] = 0.f; }
            }
        }
    };
    do_prefetch(0);

    float acc = 0.f;
    const float inv121 = 1.0f / 121.0f;
    const int r    = tid >> 6;
    const int lane = tid & 63;
    const int kb   = r & 1;
    const int base = ((r >> 1) * 320) + lane * 5;   // slots [base, base+14]
    int rs = 0;   // ring slot of the row leaving/entering at k=0 of this group

#pragma clang loop unroll(disable)
    for (int g = 0; g < GROUPS; ++g) {
        // consume this group's prefetched rows, then immediately issue next
        // group's loads -> VMEM latency overlaps rest of A + barrier + B
        float cP[3][2], cT[3][2];
#pragma unroll
        for (int c = 0; c < 3; ++c)
#pragma unroll
            for (int k = 0; k < 2; ++k) { cP[c][k] = pfP[c][k]; cT[c][k] = pfT[c][k]; }

        if (g + 1 < GROUPS) do_prefetch(g + 1);

        // ---- Phase A: advance 2 rows; subtract old from LDS ring, add new;
        //      cs writes are 2x ds_write_b64 per (c,k) instead of 4x b32
#pragma unroll
        for (int c = 0; c < 3; ++c) {
            int x = tid + (c << 8);
            if (x < WIDTH) {
#pragma unroll
                for (int k = 0; k < 2; ++k) {
                    int slot = rs + k; if (slot >= 11) slot -= 11;
                    __half2 hn = packh2(cP[c][k], cT[c][k]);
                    __half2 ho = ring[slot][x];
                    ring[slot][x] = hn;
                    float2 nq = __half22float2(hn);   // use quantized value
                    float2 o2 = __half22float2(ho);
                    S01[c] = f2add(S01[c], f2sub(nq, o2));
                    float2 pn = make_float2(nq.x*nq.x + nq.y*nq.y, nq.x*nq.y);
                    float2 po = make_float2(o2.x*o2.x + o2.y*o2.y, o2.x*o2.y);
                    S23[c] = f2add(S23[c], f2sub(pn, po));
                    csA[k][x + 5] = S01[c];
                    csB[k][x + 5] = S23[c];
                }
            }
        }
        __syncthreads();

        // ---- Phase B: 4 waves = 2 rows x 2 halves; 5 px/lane. Full 15-slot
        //      window read once as b64 pairs (30 ds-instr, loop-invariant
        //      addresses), then the rolling 11-window lives in registers.
        {
            float2 a[15], b[15];
#pragma unroll
            for (int j = 0; j < 15; ++j) {
                a[j] = csA[kb][base + j];
                b[j] = csB[kb][base + j];
            }
            float2 A = a[0], Bv = b[0];
#pragma unroll
            for (int j = 1; j < 11; ++j) { A = f2add(A, a[j]); Bv = f2add(Bv, b[j]); }
#pragma unroll
            for (int i = 0; i < 5; ++i) {
                if (i > 0) {
                    A  = f2add(A,  f2sub(a[10 + i], a[i - 1]));
                    Bv = f2add(Bv, f2sub(b[10 + i], b[i - 1]));
                }
                float mp  = A.x * inv121, mt = A.y * inv121;
                float mpp = mp*mp, mtt = mt*mt, mpt = mp*mt;
                float s2  = Bv.x * inv121 - mpp - mtt;   // sigma_p + sigma_t
                float spt = Bv.y * inv121 - mpt;         // sigma_pt
                float num = (2.f*mpt + SSIM_C1) * (2.f*spt + SSIM_C2);
                float den = (mpp + mtt + SSIM_C1) * (s2 + SSIM_C2);
                acc += num * __builtin_amdgcn_rcpf(den);
            }
        }
        __syncthreads();

        rs += 2; if (rs >= 11) rs -= 11;
    }

    // ---- block reduction -> one plain store per block (no atomics)
#pragma unroll
    for (int off = 32; off >= 1; off >>= 1)
        acc += __shfl_down(acc, off);
    if ((tid & 63) == 0) red[tid >> 6] = acc;
    __syncthreads();
    if (tid == 0)
        ws[blockIdx.x] = red[0] + red[1] + red[2] + red[3];
}

__global__ void ssim_reduce(const float* __restrict__ ws, float* __restrict__ out)
{
    __shared__ float red[4];
    const int tid = threadIdx.x;
    float s = ws[tid] + ws[tid + 256] + ws[tid + 512];
#pragma unroll
    for (int off = 32; off >= 1; off >>= 1)
        s += __shfl_down(s, off);
    if ((tid & 63) == 0) red[tid >> 6] = s;
    __syncthreads();
    if (tid == 0)
        out[0] = 1.0f - (red[0] + red[1] + red[2] + red[3]) * INV_N;
}

extern "C" void kernel_launch(void* const* d_in, const int* in_sizes, int n_in,
                              void* d_out, int out_size, void* d_ws, size_t ws_size,
                              hipStream_t stream) {
    const float* pred = (const float*)d_in[0];
    const float* targ = (const float*)d_in[1];
    float* out = (float*)d_out;
    float* ws  = (float*)d_ws;          // 768 floats of partial sums
    ssim_main<<<NBLK, 256, 0, stream>>>(pred, targ, ws);
    ssim_reduce<<<1, 256, 0, stream>>>(ws, out);
}